// Round 11
// baseline (324.092 us; speedup 1.0000x reference)
//
#include <hip/hip_runtime.h>
#include <hip/hip_bf16.h>
#include <cstdint>

typedef unsigned short ushort_t;
typedef __bf16  bf16x8 __attribute__((ext_vector_type(8)));
typedef float   f32x4  __attribute__((ext_vector_type(4)));

#define L_SEQ 2048
#define C_DIM 512
#define B_SZ  8
#define N_GROUPS 8
#define CG 64            // C / GROUPS

__device__ __forceinline__ float bf2f(ushort_t u) {
    union { uint32_t i; float f; } x; x.i = ((uint32_t)u) << 16; return x.f;
}
__device__ __forceinline__ ushort_t f2bf(float f) {
    union { float f; uint32_t i; } x; x.f = f;
    uint32_t i = x.i;
    uint32_t r = (i + 0x7FFFu + ((i >> 16) & 1u)) >> 16;
    return (ushort_t)r;
}

// async global->LDS, 16B per lane: lds dst = uniform base + lane*16, global src = per-lane ptr
__device__ __forceinline__ void gl_lds16(const ushort_t* g, ushort_t* l) {
    __builtin_amdgcn_global_load_lds(
        (const __attribute__((address_space(1))) unsigned int*)g,
        (__attribute__((address_space(3))) unsigned int*)l, 16, 0, 0);
}

// ------- fused: convert+transpose weights (blocks 0-255) | GroupNorm stats (blocks 256-767)
__global__ __launch_bounds__(256) void conv_stats(const float* __restrict__ wq,
                                                  const float* __restrict__ wk,
                                                  const float* __restrict__ wv,
                                                  const float* __restrict__ wp,
                                                  ushort_t* __restrict__ wqkvT,
                                                  ushort_t* __restrict__ wpT,
                                                  const float* __restrict__ x,
                                                  float* __restrict__ sums) {
    int tid = threadIdx.x;
    if (blockIdx.x < 256) {
        __shared__ ushort_t Ts[64][72];
        int blk = blockIdx.x;
        int mat = blk >> 6, t = blk & 63;
        int k0 = (t >> 3) * 64, n0 = (t & 7) * 64;
        const float* srcs[4] = {wq, wk, wv, wp};
        const float* src = srcs[mat];
        #pragma unroll
        for (int i = 0; i < 2; ++i) {
            int idx = tid * 2 + i;
            int row = idx >> 3, c8 = (idx & 7) * 8;
            const float* p = src + (size_t)(k0 + row) * 512 + n0 + c8;
            float4 a = *(const float4*)p;
            float4 b = *(const float4*)(p + 4);
            Ts[row][c8 + 0] = f2bf(a.x); Ts[row][c8 + 1] = f2bf(a.y);
            Ts[row][c8 + 2] = f2bf(a.z); Ts[row][c8 + 3] = f2bf(a.w);
            Ts[row][c8 + 4] = f2bf(b.x); Ts[row][c8 + 5] = f2bf(b.y);
            Ts[row][c8 + 6] = f2bf(b.z); Ts[row][c8 + 7] = f2bf(b.w);
        }
        __syncthreads();
        int dr = tid >> 2, lc = (tid & 3) * 16;
        union { uint4 v[2]; ushort_t u[16]; } o;
        #pragma unroll
        for (int j = 0; j < 16; ++j) o.u[j] = Ts[lc + j][dr];
        ushort_t* dst = (mat == 3 ? wpT + (size_t)(n0 + dr) * 512
                                  : wqkvT + (size_t)(mat * 512 + n0 + dr) * 512) + k0 + lc;
        *(uint4*)dst = o.v[0];
        *(uint4*)(dst + 8) = o.v[1];
    } else {
        int bid = blockIdx.x - 256;
        int bg = bid >> 3, sp = bid & 7;
        int b = bg >> 3, g = bg & 7;
        const float* base = x + ((size_t)b * L_SEQ + sp * 256) * C_DIM + g * CG;
        float s = 0.f, s2 = 0.f;
        #pragma unroll
        for (int it = 0; it < 8; ++it) {
            int i = it * 2048 + tid * 8;
            int l = i >> 6, c = i & 63;
            const float* p = base + (size_t)l * C_DIM + c;
            float4 a = *(const float4*)p;
            float4 bb = *(const float4*)(p + 4);
            s  += a.x + a.y + a.z + a.w + bb.x + bb.y + bb.z + bb.w;
            s2 += a.x*a.x + a.y*a.y + a.z*a.z + a.w*a.w
                + bb.x*bb.x + bb.y*bb.y + bb.z*bb.z + bb.w*bb.w;
        }
        #pragma unroll
        for (int off = 32; off > 0; off >>= 1) { s += __shfl_down(s, off); s2 += __shfl_down(s2, off); }
        __shared__ float rs[4], rs2[4];
        int wave = tid >> 6;
        if ((tid & 63) == 0) { rs[wave] = s; rs2[wave] = s2; }
        __syncthreads();
        if (tid == 0) {
            sums[bg * 16 + sp * 2 + 0] = rs[0] + rs[1] + rs[2] + rs[3];
            sums[bg * 16 + sp * 2 + 1] = rs2[0] + rs2[1] + rs2[2] + rs2[3];
        }
    }
}

// ---------------- GroupNorm apply: fp32 x -> bf16 h ----------------
__global__ __launch_bounds__(256) void gn_apply(const float* __restrict__ x,
                                                const float* __restrict__ gamma,
                                                const float* __restrict__ beta,
                                                const float* __restrict__ sums,
                                                ushort_t* __restrict__ h) {
    size_t e = ((size_t)blockIdx.x * 256 + threadIdx.x) * 8;
    int c = (int)(e % C_DIM);
    size_t bl = e / C_DIM;
    int b = (int)(bl / L_SEQ);
    int g = c >> 6;
    int bg = b * 8 + g;
    float s = 0.f, s2 = 0.f;
    #pragma unroll
    for (int sp = 0; sp < 8; ++sp) { s += sums[bg * 16 + sp * 2]; s2 += sums[bg * 16 + sp * 2 + 1]; }
    const float N = (float)(L_SEQ * CG);
    float mean = s / N;
    float var  = s2 / N - mean * mean;
    float rstd = rsqrtf(var + 1e-3f);
    float4 a = *(const float4*)(x + e);
    float4 bb = *(const float4*)(x + e + 4);
    float xf[8] = {a.x, a.y, a.z, a.w, bb.x, bb.y, bb.z, bb.w};
    union { uint4 v; ushort_t u[8]; } o;
    #pragma unroll
    for (int i = 0; i < 8; ++i)
        o.u[i] = f2bf((xf[i] - mean) * rstd * gamma[c + i] + beta[c + i]);
    *(uint4*)(h + e) = o.v;
}

// ------ fused QKV GEMM, one launch, XCD-swizzled (T1), BK=32 double-buffered (T3-2ph) ------
// Blocks 0-1023: QK gemm (A=h [16384][512], BT=wqkvT rows 0-1023, out qb/kb).
// Blocks 1024-1535: V^T gemm (A=wvT [512][512], BT=h, out vtb[b][d][l] transposed address).
// Inner loop: stage tile kt+1 into buf^1 (async DMA), compute tile kt from buf, ONE barrier
// per K-step — DMA latency hides under the 16-MFMA block.  [128][32] tiles are at the
// structural 8-phase LDS floor (bank = 16*row + 4*quad), no swizzle needed.  LDS 32 KB.
__global__ __launch_bounds__(256) void gemm_qkv(const ushort_t* __restrict__ h,
                                                const ushort_t* __restrict__ wqkvT,
                                                const float* __restrict__ bq,
                                                const float* __restrict__ bk,
                                                const float* __restrict__ bv,
                                                ushort_t* __restrict__ qb,
                                                ushort_t* __restrict__ kb,
                                                ushort_t* __restrict__ vtb) {
    __shared__ ushort_t As[2][128][32];   // 16 KB
    __shared__ ushort_t Bs[2][128][32];   // 16 KB
    int id = blockIdx.x;
    const ushort_t *A, *BT;
    int m0, n0g, vmode;
    if (id < 1024) {
        int swz = (id & 7) * 128 + (id >> 3);
        n0g = (swz & 7) * 128;           // over 1024 (q|k)
        m0  = (swz >> 3) * 128;          // over 16384
        A = h; BT = wqkvT; vmode = 0;
    } else {
        int vid = id - 1024;
        int swz = (vid & 7) * 64 + (vid >> 3);
        n0g = (swz >> 2) * 128;          // over 16384 (b,l)
        m0  = (swz & 3) * 128;           // over 512 (d)
        A = wqkvT + 2 * (size_t)C_DIM * C_DIM; BT = h; vmode = 1;
    }
    int tid = threadIdx.x, lane = tid & 63, w = tid >> 6;
    int l15 = lane & 15, quad = lane >> 4;
    int wm = w >> 1, wn = w & 1;
    int sr = lane >> 2;                  // staging row-within-16-group
    int sc = (lane & 3) * 8;             // staging chunk (elems)
    f32x4 acc[4][4] = {};
    // prologue: stage K-step 0 into buffer 0
    #pragma unroll
    for (int j = 0; j < 2; ++j) {
        int rb = j * 64 + w * 16;
        gl_lds16(A  + (size_t)(m0  + rb + sr) * 512 + sc, &As[0][rb][0]);
        gl_lds16(BT + (size_t)(n0g + rb + sr) * 512 + sc, &Bs[0][rb][0]);
    }
    __syncthreads();
    for (int kt = 0; kt < 16; ++kt) {
        int cur = kt & 1;
        if (kt < 15) {                   // stage NEXT K-step while computing this one
            int k0 = (kt + 1) * 32;
            #pragma unroll
            for (int j = 0; j < 2; ++j) {
                int rb = j * 64 + w * 16;
                gl_lds16(A  + (size_t)(m0  + rb + sr) * 512 + k0 + sc, &As[cur ^ 1][rb][0]);
                gl_lds16(BT + (size_t)(n0g + rb + sr) * 512 + k0 + sc, &Bs[cur ^ 1][rb][0]);
            }
        }
        bf16x8 af[4], bf[4];
        #pragma unroll
        for (int t = 0; t < 4; ++t) {
            af[t] = *(const bf16x8*)&As[cur][wm * 64 + t * 16 + l15][quad * 8];
            bf[t] = *(const bf16x8*)&Bs[cur][wn * 64 + t * 16 + l15][quad * 8];
        }
        #pragma unroll
        for (int mt = 0; mt < 4; ++mt)
            #pragma unroll
            for (int nt = 0; nt < 4; ++nt)
                acc[mt][nt] = __builtin_amdgcn_mfma_f32_16x16x32_bf16(af[mt], bf[nt], acc[mt][nt], 0, 0, 0);
        __syncthreads();                 // drains next-tile DMA + protects buf reuse
    }
    if (vmode == 0) {
        int seg = n0g >> 9;
        const float* bias = seg ? bk : bq;
        ushort_t* ob = seg ? kb : qb;
        int ns = n0g & 511;
        #pragma unroll
        for (int mt = 0; mt < 4; ++mt)
            #pragma unroll
            for (int nt = 0; nt < 4; ++nt) {
                int n = ns + wn * 64 + nt * 16 + l15;
                float bvn = bias[n];
                #pragma unroll
                for (int r = 0; r < 4; ++r) {
                    int m = m0 + wm * 64 + mt * 16 + quad * 4 + r;
                    ob[(size_t)m * 512 + n] = f2bf(acc[mt][nt][r] + bvn);
                }
            }
    } else {
        #pragma unroll
        for (int mt = 0; mt < 4; ++mt)
            #pragma unroll
            for (int nt = 0; nt < 4; ++nt) {
                int n = n0g + wn * 64 + nt * 16 + l15;
                #pragma unroll
                for (int r = 0; r < 4; ++r) {
                    int m = m0 + wm * 64 + mt * 16 + quad * 4 + r;
                    float v = acc[mt][nt][r] + bv[m];
                    vtb[(size_t)(n >> 11) * 1048576 + (size_t)m * 2048 + (n & 2047)] = f2bf(v);
                }
            }
    }
}

// ---------------- PROJ GEMM: f32 out + bf16 residual, XCD-swizzled, BK=32 dbuf ------------
__global__ __launch_bounds__(256) void gemm_proj(const ushort_t* __restrict__ A,
                                                 const ushort_t* __restrict__ BT,
                                                 const float* __restrict__ b0,
                                                 const ushort_t* __restrict__ res,
                                                 float* __restrict__ of) {
    __shared__ ushort_t As[2][128][32];
    __shared__ ushort_t Bs[2][128][32];
    int id = blockIdx.x;                  // 512 blocks
    int swz = (id & 7) * 64 + (id >> 3);  // bijective; same-m-panel blocks on one XCD
    int n0g = (swz & 3) * 128;            // over 512
    int m0  = (swz >> 2) * 128;           // over 16384
    int tid = threadIdx.x, lane = tid & 63, w = tid >> 6;
    int l15 = lane & 15, quad = lane >> 4;
    int wm = w >> 1, wn = w & 1;
    int sr = lane >> 2;
    int sc = (lane & 3) * 8;
    f32x4 acc[4][4] = {};
    #pragma unroll
    for (int j = 0; j < 2; ++j) {
        int rb = j * 64 + w * 16;
        gl_lds16(A  + (size_t)(m0  + rb + sr) * 512 + sc, &As[0][rb][0]);
        gl_lds16(BT + (size_t)(n0g + rb + sr) * 512 + sc, &Bs[0][rb][0]);
    }
    __syncthreads();
    for (int kt = 0; kt < 16; ++kt) {
        int cur = kt & 1;
        if (kt < 15) {
            int k0 = (kt + 1) * 32;
            #pragma unroll
            for (int j = 0; j < 2; ++j) {
                int rb = j * 64 + w * 16;
                gl_lds16(A  + (size_t)(m0  + rb + sr) * 512 + k0 + sc, &As[cur ^ 1][rb][0]);
                gl_lds16(BT + (size_t)(n0g + rb + sr) * 512 + k0 + sc, &Bs[cur ^ 1][rb][0]);
            }
        }
        bf16x8 af[4], bf[4];
        #pragma unroll
        for (int t = 0; t < 4; ++t) {
            af[t] = *(const bf16x8*)&As[cur][wm * 64 + t * 16 + l15][quad * 8];
            bf[t] = *(const bf16x8*)&Bs[cur][wn * 64 + t * 16 + l15][quad * 8];
        }
        #pragma unroll
        for (int mt = 0; mt < 4; ++mt)
            #pragma unroll
            for (int nt = 0; nt < 4; ++nt)
                acc[mt][nt] = __builtin_amdgcn_mfma_f32_16x16x32_bf16(af[mt], bf[nt], acc[mt][nt], 0, 0, 0);
        __syncthreads();
    }
    #pragma unroll
    for (int mt = 0; mt < 4; ++mt)
        #pragma unroll
        for (int nt = 0; nt < 4; ++nt) {
            int n = n0g + wn * 64 + nt * 16 + l15;
            float bvn = b0[n];
            #pragma unroll
            for (int r = 0; r < 4; ++r) {
                int m = m0 + wm * 64 + mt * 16 + quad * 4 + r;
                of[(size_t)m * 512 + n] = acc[mt][nt][r] + bvn + bf2f(res[(size_t)m * 512 + n]);
            }
        }
}

// ---------------- Flash attention v11 (r8 verbatim): DMA K+V, 4-chain QK ------------------
// 768 threads = 12 waves (3/SIMD: 1 QK + 2 PV).  Waves 0-3: QK^T + online softmax (16
// q-rows each, swapped mfma(K,Q)), MFMA in 4 independent chains.  Waves 4-11: PV, 64-wide
// d-slices (acc = 64 VGPR).  K tile kt+1 AND V tile kt staged by PV waves via async
// global_load_lds (zero VGPR), drained by the single end-of-iter barrier.
__global__ __launch_bounds__(768, 3) void attn11(const ushort_t* __restrict__ Q,
                                                 const ushort_t* __restrict__ K,
                                                 const ushort_t* __restrict__ vT,
                                                 ushort_t* __restrict__ O) {
    __shared__ ushort_t Ks[2][32][520];   // K tiles, double-buffered (66.6 KB)
    __shared__ ushort_t Vs[2][512][32];   // V tiles [d][k], double-buffered (64 KB, linear DMA)
    __shared__ ushort_t Ps[2][64][40];    // P [q][k], stride 80B, 10.2 KB
    __shared__ float    Al[2][64];        // per-row alpha
    __shared__ float    Lb[64];           // final l per row
    int tid = threadIdx.x;
    int lane = tid & 63, w = tid >> 6;
    int l15 = lane & 15, quad = lane >> 4;
    int b  = blockIdx.x & 7;
    int qt = blockIdx.x >> 3;
    const float scale2 = 0.044194173824159216f * 1.4426950408889634f;  // 512^-.5 * log2(e)
    const ushort_t* Qb = Q + (size_t)b * L_SEQ * C_DIM;
    const ushort_t* Kb = K + (size_t)b * L_SEQ * C_DIM;
    const ushort_t* Vt = vT + (size_t)b * C_DIM * L_SEQ;
    ushort_t* Ob = O + (size_t)b * L_SEQ * C_DIM;

    bool isQK = (w < 4);
    int pw = w - 4;                       // PV wave index 0..7
    int d0 = pw * 64;                     // PV d-slice base

    bf16x8 qf[16];                        // QK: persistent Q frags (64 VGPR)
    float m_r = -1e30f, l_r = 0.f;
    f32x4 acc[4][4];                      // PV: O accum [qi][nt] = 64 VGPR

    if (isQK) {
        int qr = qt * 64 + w * 16 + l15;
        #pragma unroll
        for (int ks = 0; ks < 16; ++ks)
            qf[ks] = *(const bf16x8*)(Qb + (size_t)qr * C_DIM + ks * 32 + quad * 8);
    } else {
        #pragma unroll
        for (int qi = 0; qi < 4; ++qi)
            #pragma unroll
            for (int nt = 0; nt < 4; ++nt) acc[qi][nt] = (f32x4){0.f, 0.f, 0.f, 0.f};
        // prologue: PV waves stage K tile 0 into buffer 0 (4 rows each)
        #pragma unroll
        for (int i = 0; i < 4; ++i) {
            int row = pw * 4 + i;
            gl_lds16(Kb + (size_t)row * C_DIM + lane * 8, &Ks[0][row][0]);
        }
    }
    __syncthreads();

    for (int kt = 0; kt <= 64; ++kt) {
        int cur = kt & 1, prv = cur ^ 1;
        if (isQK) {
            if (kt < 64) {
                // S^T = K @ Q^T: lane owns q-row l15, 8 keys in regs; 4 independent chains
                f32x4 s0a = (f32x4){0.f, 0.f, 0.f, 0.f};
                f32x4 s0b = (f32x4){0.f, 0.f, 0.f, 0.f};
                f32x4 s1a = (f32x4){0.f, 0.f, 0.f, 0.f};
                f32x4 s1b = (f32x4){0.f, 0.f, 0.f, 0.f};
                __builtin_amdgcn_s_setprio(1);
                #pragma unroll
                for (int ks = 0; ks < 16; ks += 2) {
                    bf16x8 kf0 = *(const bf16x8*)&Ks[cur][l15][ks * 32 + quad * 8];
                    bf16x8 kf1 = *(const bf16x8*)&Ks[cur][16 + l15][ks * 32 + quad * 8];
                    bf16x8 kf2 = *(const bf16x8*)&Ks[cur][l15][(ks + 1) * 32 + quad * 8];
                    bf16x8 kf3 = *(const bf16x8*)&Ks[cur][16 + l15][(ks + 1) * 32 + quad * 8];
                    s0a = __builtin_amdgcn_mfma_f32_16x16x32_bf16(kf0, qf[ks], s0a, 0, 0, 0);
                    s1a = __builtin_amdgcn_mfma_f32_16x16x32_bf16(kf1, qf[ks], s1a, 0, 0, 0);
                    s0b = __builtin_amdgcn_mfma_f32_16x16x32_bf16(kf2, qf[ks + 1], s0b, 0, 0, 0);
                    s1b = __builtin_amdgcn_mfma_f32_16x16x32_bf16(kf3, qf[ks + 1], s1b, 0, 0, 0);
                }
                __builtin_amdgcn_s_setprio(0);
                f32x4 s0 = s0a + s0b;
                f32x4 s1 = s1a + s1b;
                float mx = fmaxf(fmaxf(fmaxf(s0[0], s0[1]), fmaxf(s0[2], s0[3])),
                                 fmaxf(fmaxf(s1[0], s1[1]), fmaxf(s1[2], s1[3])));
                mx = fmaxf(mx, __shfl_xor(mx, 16, 64));
                mx = fmaxf(mx, __shfl_xor(mx, 32, 64));
                mx *= scale2;
                float mn = fmaxf(m_r, mx);
                float alpha = exp2f(m_r - mn);
                m_r = mn;
                ushort_t pb[8];
                float rs = 0.f;
                #pragma unroll
                for (int r = 0; r < 4; ++r) {
                    pb[r]     = f2bf(exp2f(s0[r] * scale2 - mn));
                    pb[4 + r] = f2bf(exp2f(s1[r] * scale2 - mn));
                    rs += bf2f(pb[r]) + bf2f(pb[4 + r]);
                }
                rs += __shfl_xor(rs, 16, 64);
                rs += __shfl_xor(rs, 32, 64);
                l_r = l_r * alpha + rs;
                int row = w * 16 + l15;
                uint2 w0, w1;
                w0.x = (uint32_t)pb[0] | ((uint32_t)pb[1] << 16);
                w0.y = (uint32_t)pb[2] | ((uint32_t)pb[3] << 16);
                w1.x = (uint32_t)pb[4] | ((uint32_t)pb[5] << 16);
                w1.y = (uint32_t)pb[6] | ((uint32_t)pb[7] << 16);
                *(uint2*)&Ps[cur][row][quad * 4] = w0;
                *(uint2*)&Ps[cur][row][16 + quad * 4] = w1;
                if (lane < 16) Al[cur][w * 16 + lane] = alpha;
            } else {
                if (lane < 16) Lb[w * 16 + lane] = l_r;   // drain iter: publish l
            }
        } else {
            // ---- PV waves: issue all async staging FIRST (full-iteration latency cover)
            if (kt < 63) {                 // K tile kt+1 -> Ks[prv] (read next iter by QK)
                #pragma unroll
                for (int i = 0; i < 4; ++i) {
                    int row = pw * 4 + i;
                    gl_lds16(Kb + (size_t)((kt + 1) * 32 + row) * C_DIM + lane * 8, &Ks[prv][row][0]);
                }
            }
            if (kt < 64) {                 // V tile kt -> Vs[cur] (read next iter by PV)
                int k0 = kt * 32;
                #pragma unroll
                for (int i = 0; i < 4; ++i) {
                    int r0 = (pw * 4 + i) * 16;
                    gl_lds16(Vt + (size_t)(r0 + (lane >> 2)) * L_SEQ + k0 + (lane & 3) * 8,
                             &Vs[cur][r0][0]);
                }
            }
            if (kt > 0) {
                // ---- PV for tile kt-1 from Ps/Al/Vs[prv]
                bf16x8 pf[4];
                #pragma unroll
                for (int qi = 0; qi < 4; ++qi)
                    pf[qi] = *(const bf16x8*)&Ps[prv][qi * 16 + l15][quad * 8];
                #pragma unroll
                for (int qi = 0; qi < 4; ++qi) {
                    float4 av = *(const float4*)&Al[prv][qi * 16 + quad * 4];
                    #pragma unroll
                    for (int nt = 0; nt < 4; ++nt) {
                        acc[qi][nt][0] *= av.x; acc[qi][nt][1] *= av.y;
                        acc[qi][nt][2] *= av.z; acc[qi][nt][3] *= av.w;
                    }
                }
                bf16x8 vf[4];
                #pragma unroll
                for (int nt = 0; nt < 4; ++nt)
                    vf[nt] = *(const bf16x8*)&Vs[prv][d0 + nt * 16 + l15][quad * 8];
                __builtin_amdgcn_s_setprio(1);
                #pragma unroll
                for (int nt = 0; nt < 4; ++nt)
                    #pragma unroll
                    for (int qi = 0; qi < 4; ++qi)
                        acc[qi][nt] = __builtin_amdgcn_mfma_f32_16x16x32_bf16(pf[qi], vf[nt], acc[qi][nt], 0, 0, 0);
                __builtin_amdgcn_s_setprio(0);
            }
        }
        __syncthreads();   // P/alpha handoff + drains K & V DMA vmcnt
    }
    // epilogue: PV waves normalize and write their d-slice
    if (!isQK) {
        #pragma unroll
        for (int qi = 0; qi < 4; ++qi) {
            float4 lv = *(const float4*)&Lb[qi * 16 + quad * 4];
            float inv[4] = {1.f / lv.x, 1.f / lv.y, 1.f / lv.z, 1.f / lv.w};
            #pragma unroll
            for (int r = 0; r < 4; ++r) {
                int m = qt * 64 + qi * 16 + quad * 4 + r;
                #pragma unroll
                for (int nt = 0; nt < 4; ++nt)
                    Ob[(size_t)m * 512 + d0 + nt * 16 + l15] = f2bf(acc[qi][nt][r] * inv[r]);
            }
        }
    }
}

extern "C" void kernel_launch(void* const* d_in, const int* in_sizes, int n_in,
                              void* d_out, int out_size, void* d_ws, size_t ws_size,
                              hipStream_t stream) {
    const float* x     = (const float*)d_in[0];
    const float* gamma = (const float*)d_in[1];
    const float* beta  = (const float*)d_in[2];
    const float* wq    = (const float*)d_in[3];
    const float* bq    = (const float*)d_in[4];
    const float* wk    = (const float*)d_in[5];
    const float* bk    = (const float*)d_in[6];
    const float* wv    = (const float*)d_in[7];
    const float* bv    = (const float*)d_in[8];
    const float* wp    = (const float*)d_in[9];
    const float* bp    = (const float*)d_in[10];
    float* out = (float*)d_out;

    const size_t MC = (size_t)B_SZ * L_SEQ * C_DIM;   // 8,388,608 elems
    const size_t WC = (size_t)C_DIM * C_DIM;
    ushort_t* h     = (ushort_t*)d_ws;
    ushort_t* qb    = h     + MC;
    ushort_t* kb    = qb    + MC;
    ushort_t* vbuf  = kb    + MC;   // attention output O
    ushort_t* vtb   = vbuf  + MC;   // V^T [b][d][l] (written directly by gemm_qkv V-blocks)
    ushort_t* wqkvT = vtb   + MC;   // [1536][512] bf16 (wq^T | wk^T | wv^T)
    ushort_t* wpT   = wqkvT + 3 * WC;
    float* sums     = (float*)(wpT + WC);

    conv_stats<<<dim3(768), dim3(256), 0, stream>>>(wq, wk, wv, wp, wqkvT, wpT, x, sums);
    gn_apply<<<dim3(4096), dim3(256), 0, stream>>>(x, gamma, beta, sums, h);

    // fused QKV GEMM (QK blocks 0-1023, V^T blocks 1024-1535), XCD-swizzled, dbuf
    gemm_qkv<<<dim3(1536), dim3(256), 0, stream>>>(h, wqkvT, bq, bk, bv, qb, kb, vtb);

    attn11<<<dim3(256), dim3(768), 0, stream>>>(qb, kb, vtb, vbuf);

    // PROJ GEMM: f32 out + residual h, XCD-swizzled, dbuf
    gemm_proj<<<dim3(512), dim3(256), 0, stream>>>(vbuf, wpT, bp, h, out);
}

// Round 12
// 307.626 us; speedup vs baseline: 1.0535x; 1.0535x over previous
//
#include <hip/hip_runtime.h>
#include <hip/hip_bf16.h>
#include <cstdint>

typedef unsigned short ushort_t;
typedef __bf16  bf16x8 __attribute__((ext_vector_type(8)));
typedef float   f32x4  __attribute__((ext_vector_type(4)));

#define L_SEQ 2048
#define C_DIM 512
#define B_SZ  8
#define N_GROUPS 8
#define CG 64            // C / GROUPS

__device__ __forceinline__ float bf2f(ushort_t u) {
    union { uint32_t i; float f; } x; x.i = ((uint32_t)u) << 16; return x.f;
}
__device__ __forceinline__ ushort_t f2bf(float f) {
    union { float f; uint32_t i; } x; x.f = f;
    uint32_t i = x.i;
    uint32_t r = (i + 0x7FFFu + ((i >> 16) & 1u)) >> 16;
    return (ushort_t)r;
}

// async global->LDS, 16B per lane: lds dst = uniform base + lane*16, global src = per-lane ptr
__device__ __forceinline__ void gl_lds16(const ushort_t* g, ushort_t* l) {
    __builtin_amdgcn_global_load_lds(
        (const __attribute__((address_space(1))) unsigned int*)g,
        (__attribute__((address_space(3))) unsigned int*)l, 16, 0, 0);
}

// ------- fused: convert+transpose weights (blocks 0-255) | GroupNorm stats (blocks 256-767)
__global__ __launch_bounds__(256) void conv_stats(const float* __restrict__ wq,
                                                  const float* __restrict__ wk,
                                                  const float* __restrict__ wv,
                                                  const float* __restrict__ wp,
                                                  ushort_t* __restrict__ wqkvT,
                                                  ushort_t* __restrict__ wpT,
                                                  const float* __restrict__ x,
                                                  float* __restrict__ sums) {
    int tid = threadIdx.x;
    if (blockIdx.x < 256) {
        __shared__ ushort_t Ts[64][72];
        int blk = blockIdx.x;
        int mat = blk >> 6, t = blk & 63;
        int k0 = (t >> 3) * 64, n0 = (t & 7) * 64;
        const float* srcs[4] = {wq, wk, wv, wp};
        const float* src = srcs[mat];
        #pragma unroll
        for (int i = 0; i < 2; ++i) {
            int idx = tid * 2 + i;
            int row = idx >> 3, c8 = (idx & 7) * 8;
            const float* p = src + (size_t)(k0 + row) * 512 + n0 + c8;
            float4 a = *(const float4*)p;
            float4 b = *(const float4*)(p + 4);
            Ts[row][c8 + 0] = f2bf(a.x); Ts[row][c8 + 1] = f2bf(a.y);
            Ts[row][c8 + 2] = f2bf(a.z); Ts[row][c8 + 3] = f2bf(a.w);
            Ts[row][c8 + 4] = f2bf(b.x); Ts[row][c8 + 5] = f2bf(b.y);
            Ts[row][c8 + 6] = f2bf(b.z); Ts[row][c8 + 7] = f2bf(b.w);
        }
        __syncthreads();
        int dr = tid >> 2, lc = (tid & 3) * 16;
        union { uint4 v[2]; ushort_t u[16]; } o;
        #pragma unroll
        for (int j = 0; j < 16; ++j) o.u[j] = Ts[lc + j][dr];
        ushort_t* dst = (mat == 3 ? wpT + (size_t)(n0 + dr) * 512
                                  : wqkvT + (size_t)(mat * 512 + n0 + dr) * 512) + k0 + lc;
        *(uint4*)dst = o.v[0];
        *(uint4*)(dst + 8) = o.v[1];
    } else {
        int bid = blockIdx.x - 256;
        int bg = bid >> 3, sp = bid & 7;
        int b = bg >> 3, g = bg & 7;
        const float* base = x + ((size_t)b * L_SEQ + sp * 256) * C_DIM + g * CG;
        float s = 0.f, s2 = 0.f;
        #pragma unroll
        for (int it = 0; it < 8; ++it) {
            int i = it * 2048 + tid * 8;
            int l = i >> 6, c = i & 63;
            const float* p = base + (size_t)l * C_DIM + c;
            float4 a = *(const float4*)p;
            float4 bb = *(const float4*)(p + 4);
            s  += a.x + a.y + a.z + a.w + bb.x + bb.y + bb.z + bb.w;
            s2 += a.x*a.x + a.y*a.y + a.z*a.z + a.w*a.w
                + bb.x*bb.x + bb.y*bb.y + bb.z*bb.z + bb.w*bb.w;
        }
        #pragma unroll
        for (int off = 32; off > 0; off >>= 1) { s += __shfl_down(s, off); s2 += __shfl_down(s2, off); }
        __shared__ float rs[4], rs2[4];
        int wave = tid >> 6;
        if ((tid & 63) == 0) { rs[wave] = s; rs2[wave] = s2; }
        __syncthreads();
        if (tid == 0) {
            sums[bg * 16 + sp * 2 + 0] = rs[0] + rs[1] + rs[2] + rs[3];
            sums[bg * 16 + sp * 2 + 1] = rs2[0] + rs2[1] + rs2[2] + rs2[3];
        }
    }
}

// ---------------- GroupNorm apply: fp32 x -> bf16 h ----------------
__global__ __launch_bounds__(256) void gn_apply(const float* __restrict__ x,
                                                const float* __restrict__ gamma,
                                                const float* __restrict__ beta,
                                                const float* __restrict__ sums,
                                                ushort_t* __restrict__ h) {
    size_t e = ((size_t)blockIdx.x * 256 + threadIdx.x) * 8;
    int c = (int)(e % C_DIM);
    size_t bl = e / C_DIM;
    int b = (int)(bl / L_SEQ);
    int g = c >> 6;
    int bg = b * 8 + g;
    float s = 0.f, s2 = 0.f;
    #pragma unroll
    for (int sp = 0; sp < 8; ++sp) { s += sums[bg * 16 + sp * 2]; s2 += sums[bg * 16 + sp * 2 + 1]; }
    const float N = (float)(L_SEQ * CG);
    float mean = s / N;
    float var  = s2 / N - mean * mean;
    float rstd = rsqrtf(var + 1e-3f);
    float4 a = *(const float4*)(x + e);
    float4 bb = *(const float4*)(x + e + 4);
    float xf[8] = {a.x, a.y, a.z, a.w, bb.x, bb.y, bb.z, bb.w};
    union { uint4 v; ushort_t u[8]; } o;
    #pragma unroll
    for (int i = 0; i < 8; ++i)
        o.u[i] = f2bf((xf[i] - mean) * rstd * gamma[c + i] + beta[c + i]);
    *(uint4*)(h + e) = o.v;
}

// ------ fused QKV GEMM, one launch, XCD-swizzled (T1), BK=64 + both-sides XOR swizzle -----
// Blocks 0-1023: QK gemm (A=h [16384][512], BT=wqkvT rows 0-1023, out qb/kb).
// Blocks 1024-1535: V^T gemm (A=wvT [512][512], BT=h, out vtb[b][d][l] transposed address).
// r10-verified structure: stage -> barrier -> 2x16 MFMA -> barrier; at 4-5 blocks/CU the
// staging DMA hides under other blocks' compute (m114).  Explicit dbuf regressed (r11, m99).
__global__ __launch_bounds__(256) void gemm_qkv(const ushort_t* __restrict__ h,
                                                const ushort_t* __restrict__ wqkvT,
                                                const float* __restrict__ bq,
                                                const float* __restrict__ bk,
                                                const float* __restrict__ bv,
                                                ushort_t* __restrict__ qb,
                                                ushort_t* __restrict__ kb,
                                                ushort_t* __restrict__ vtb) {
    __shared__ ushort_t As[128][64];   // 16 KB
    __shared__ ushort_t Bs[128][64];   // 16 KB
    int id = blockIdx.x;
    const ushort_t *A, *BT;
    int m0, n0g, vmode;
    if (id < 1024) {
        int swz = (id & 7) * 128 + (id >> 3);
        n0g = (swz & 7) * 128;           // over 1024 (q|k)
        m0  = (swz >> 3) * 128;          // over 16384
        A = h; BT = wqkvT; vmode = 0;
    } else {
        int vid = id - 1024;
        int swz = (vid & 7) * 64 + (vid >> 3);
        n0g = (swz >> 2) * 128;          // over 16384 (b,l)
        m0  = (swz & 3) * 128;           // over 512 (d)
        A = wqkvT + 2 * (size_t)C_DIM * C_DIM; BT = h; vmode = 1;
    }
    int tid = threadIdx.x, lane = tid & 63, w = tid >> 6;
    int l15 = lane & 15, quad = lane >> 4;
    int wm = w >> 1, wn = w & 1;
    int lr8 = lane >> 3;
    int gch = (lane & 7) ^ lr8;
    int h8  = l15 & 7;
    f32x4 acc[4][4] = {};
    for (int k0 = 0; k0 < 512; k0 += 64) {
        #pragma unroll
        for (int j = 0; j < 4; ++j) {
            int rb = w * 32 + j * 8;
            int r  = rb + lr8;
            gl_lds16(A  + (size_t)(m0 + r) * 512 + k0 + gch * 8, &As[rb][0]);
            gl_lds16(BT + (size_t)(n0g + r) * 512 + k0 + gch * 8, &Bs[rb][0]);
        }
        __syncthreads();
        #pragma unroll
        for (int kk = 0; kk < 2; ++kk) {
            int slot = ((quad + 4 * kk) ^ h8) * 8;
            bf16x8 af[4], bf[4];
            #pragma unroll
            for (int t = 0; t < 4; ++t) {
                af[t] = *(const bf16x8*)&As[wm * 64 + t * 16 + l15][slot];
                bf[t] = *(const bf16x8*)&Bs[wn * 64 + t * 16 + l15][slot];
            }
            #pragma unroll
            for (int mt = 0; mt < 4; ++mt)
                #pragma unroll
                for (int nt = 0; nt < 4; ++nt)
                    acc[mt][nt] = __builtin_amdgcn_mfma_f32_16x16x32_bf16(af[mt], bf[nt], acc[mt][nt], 0, 0, 0);
        }
        __syncthreads();
    }
    if (vmode == 0) {
        int seg = n0g >> 9;
        const float* bias = seg ? bk : bq;
        ushort_t* ob = seg ? kb : qb;
        int ns = n0g & 511;
        #pragma unroll
        for (int mt = 0; mt < 4; ++mt)
            #pragma unroll
            for (int nt = 0; nt < 4; ++nt) {
                int n = ns + wn * 64 + nt * 16 + l15;
                float bvn = bias[n];
                #pragma unroll
                for (int r = 0; r < 4; ++r) {
                    int m = m0 + wm * 64 + mt * 16 + quad * 4 + r;
                    ob[(size_t)m * 512 + n] = f2bf(acc[mt][nt][r] + bvn);
                }
            }
    } else {
        #pragma unroll
        for (int mt = 0; mt < 4; ++mt)
            #pragma unroll
            for (int nt = 0; nt < 4; ++nt) {
                int n = n0g + wn * 64 + nt * 16 + l15;
                #pragma unroll
                for (int r = 0; r < 4; ++r) {
                    int m = m0 + wm * 64 + mt * 16 + quad * 4 + r;
                    float v = acc[mt][nt][r] + bv[m];
                    vtb[(size_t)(n >> 11) * 1048576 + (size_t)m * 2048 + (n & 2047)] = f2bf(v);
                }
            }
    }
}

// ---------------- PROJ GEMM: f32 out + bf16 residual, XCD-swizzled -------------------------
__global__ __launch_bounds__(256) void gemm_proj(const ushort_t* __restrict__ A,
                                                 const ushort_t* __restrict__ BT,
                                                 const float* __restrict__ b0,
                                                 const ushort_t* __restrict__ res,
                                                 float* __restrict__ of) {
    __shared__ ushort_t As[128][64];
    __shared__ ushort_t Bs[128][64];
    int id = blockIdx.x;                  // 512 blocks
    int swz = (id & 7) * 64 + (id >> 3);  // bijective; same-m-panel blocks on one XCD
    int n0g = (swz & 3) * 128;            // over 512
    int m0  = (swz >> 2) * 128;           // over 16384
    int tid = threadIdx.x, lane = tid & 63, w = tid >> 6;
    int l15 = lane & 15, quad = lane >> 4;
    int wm = w >> 1, wn = w & 1;
    int lr8 = lane >> 3;
    int gch = (lane & 7) ^ lr8;
    int h8  = l15 & 7;
    f32x4 acc[4][4] = {};
    for (int k0 = 0; k0 < 512; k0 += 64) {
        #pragma unroll
        for (int j = 0; j < 4; ++j) {
            int rb = w * 32 + j * 8;
            int r  = rb + lr8;
            gl_lds16(A  + (size_t)(m0 + r) * 512 + k0 + gch * 8, &As[rb][0]);
            gl_lds16(BT + (size_t)(n0g + r) * 512 + k0 + gch * 8, &Bs[rb][0]);
        }
        __syncthreads();
        #pragma unroll
        for (int kk = 0; kk < 2; ++kk) {
            int slot = ((quad + 4 * kk) ^ h8) * 8;
            bf16x8 af[4], bf[4];
            #pragma unroll
            for (int t = 0; t < 4; ++t) {
                af[t] = *(const bf16x8*)&As[wm * 64 + t * 16 + l15][slot];
                bf[t] = *(const bf16x8*)&Bs[wn * 64 + t * 16 + l15][slot];
            }
            #pragma unroll
            for (int mt = 0; mt < 4; ++mt)
                #pragma unroll
                for (int nt = 0; nt < 4; ++nt)
                    acc[mt][nt] = __builtin_amdgcn_mfma_f32_16x16x32_bf16(af[mt], bf[nt], acc[mt][nt], 0, 0, 0);
        }
        __syncthreads();
    }
    #pragma unroll
    for (int mt = 0; mt < 4; ++mt)
        #pragma unroll
        for (int nt = 0; nt < 4; ++nt) {
            int n = n0g + wn * 64 + nt * 16 + l15;
            float bvn = b0[n];
            #pragma unroll
            for (int r = 0; r < 4; ++r) {
                int m = m0 + wm * 64 + mt * 16 + quad * 4 + r;
                of[(size_t)m * 512 + n] = acc[mt][nt][r] + bvn + bf2f(res[(size_t)m * 512 + n]);
            }
        }
}

// ---------------- Flash attention v11 (r8 verbatim): DMA K+V, 4-chain QK ------------------
// 768 threads = 12 waves (3/SIMD: 1 QK + 2 PV).  Waves 0-3: QK^T + online softmax (16
// q-rows each, swapped mfma(K,Q)), MFMA in 4 independent chains.  Waves 4-11: PV, 64-wide
// d-slices (acc = 64 VGPR).  K tile kt+1 AND V tile kt staged by PV waves via async
// global_load_lds (zero VGPR), drained by the single end-of-iter barrier.
__global__ __launch_bounds__(768, 3) void attn11(const ushort_t* __restrict__ Q,
                                                 const ushort_t* __restrict__ K,
                                                 const ushort_t* __restrict__ vT,
                                                 ushort_t* __restrict__ O) {
    __shared__ ushort_t Ks[2][32][520];   // K tiles, double-buffered (66.6 KB)
    __shared__ ushort_t Vs[2][512][32];   // V tiles [d][k], double-buffered (64 KB, linear DMA)
    __shared__ ushort_t Ps[2][64][40];    // P [q][k], stride 80B, 10.2 KB
    __shared__ float    Al[2][64];        // per-row alpha
    __shared__ float    Lb[64];           // final l per row
    int tid = threadIdx.x;
    int lane = tid & 63, w = tid >> 6;
    int l15 = lane & 15, quad = lane >> 4;
    int b  = blockIdx.x & 7;
    int qt = blockIdx.x >> 3;
    const float scale2 = 0.044194173824159216f * 1.4426950408889634f;  // 512^-.5 * log2(e)
    const ushort_t* Qb = Q + (size_t)b * L_SEQ * C_DIM;
    const ushort_t* Kb = K + (size_t)b * L_SEQ * C_DIM;
    const ushort_t* Vt = vT + (size_t)b * C_DIM * L_SEQ;
    ushort_t* Ob = O + (size_t)b * L_SEQ * C_DIM;

    bool isQK = (w < 4);
    int pw = w - 4;                       // PV wave index 0..7
    int d0 = pw * 64;                     // PV d-slice base

    bf16x8 qf[16];                        // QK: persistent Q frags (64 VGPR)
    float m_r = -1e30f, l_r = 0.f;
    f32x4 acc[4][4];                      // PV: O accum [qi][nt] = 64 VGPR

    if (isQK) {
        int qr = qt * 64 + w * 16 + l15;
        #pragma unroll
        for (int ks = 0; ks < 16; ++ks)
            qf[ks] = *(const bf16x8*)(Qb + (size_t)qr * C_DIM + ks * 32 + quad * 8);
    } else {
        #pragma unroll
        for (int qi = 0; qi < 4; ++qi)
            #pragma unroll
            for (int nt = 0; nt < 4; ++nt) acc[qi][nt] = (f32x4){0.f, 0.f, 0.f, 0.f};
        // prologue: PV waves stage K tile 0 into buffer 0 (4 rows each)
        #pragma unroll
        for (int i = 0; i < 4; ++i) {
            int row = pw * 4 + i;
            gl_lds16(Kb + (size_t)row * C_DIM + lane * 8, &Ks[0][row][0]);
        }
    }
    __syncthreads();

    for (int kt = 0; kt <= 64; ++kt) {
        int cur = kt & 1, prv = cur ^ 1;
        if (isQK) {
            if (kt < 64) {
                // S^T = K @ Q^T: lane owns q-row l15, 8 keys in regs; 4 independent chains
                f32x4 s0a = (f32x4){0.f, 0.f, 0.f, 0.f};
                f32x4 s0b = (f32x4){0.f, 0.f, 0.f, 0.f};
                f32x4 s1a = (f32x4){0.f, 0.f, 0.f, 0.f};
                f32x4 s1b = (f32x4){0.f, 0.f, 0.f, 0.f};
                __builtin_amdgcn_s_setprio(1);
                #pragma unroll
                for (int ks = 0; ks < 16; ks += 2) {
                    bf16x8 kf0 = *(const bf16x8*)&Ks[cur][l15][ks * 32 + quad * 8];
                    bf16x8 kf1 = *(const bf16x8*)&Ks[cur][16 + l15][ks * 32 + quad * 8];
                    bf16x8 kf2 = *(const bf16x8*)&Ks[cur][l15][(ks + 1) * 32 + quad * 8];
                    bf16x8 kf3 = *(const bf16x8*)&Ks[cur][16 + l15][(ks + 1) * 32 + quad * 8];
                    s0a = __builtin_amdgcn_mfma_f32_16x16x32_bf16(kf0, qf[ks], s0a, 0, 0, 0);
                    s1a = __builtin_amdgcn_mfma_f32_16x16x32_bf16(kf1, qf[ks], s1a, 0, 0, 0);
                    s0b = __builtin_amdgcn_mfma_f32_16x16x32_bf16(kf2, qf[ks + 1], s0b, 0, 0, 0);
                    s1b = __builtin_amdgcn_mfma_f32_16x16x32_bf16(kf3, qf[ks + 1], s1b, 0, 0, 0);
                }
                __builtin_amdgcn_s_setprio(0);
                f32x4 s0 = s0a + s0b;
                f32x4 s1 = s1a + s1b;
                float mx = fmaxf(fmaxf(fmaxf(s0[0], s0[1]), fmaxf(s0[2], s0[3])),
                                 fmaxf(fmaxf(s1[0], s1[1]), fmaxf(s1[2], s1[3])));
                mx = fmaxf(mx, __shfl_xor(mx, 16, 64));
                mx = fmaxf(mx, __shfl_xor(mx, 32, 64));
                mx *= scale2;
                float mn = fmaxf(m_r, mx);
                float alpha = exp2f(m_r - mn);
                m_r = mn;
                ushort_t pb[8];
                float rs = 0.f;
                #pragma unroll
                for (int r = 0; r < 4; ++r) {
                    pb[r]     = f2bf(exp2f(s0[r] * scale2 - mn));
                    pb[4 + r] = f2bf(exp2f(s1[r] * scale2 - mn));
                    rs += bf2f(pb[r]) + bf2f(pb[4 + r]);
                }
                rs += __shfl_xor(rs, 16, 64);
                rs += __shfl_xor(rs, 32, 64);
                l_r = l_r * alpha + rs;
                int row = w * 16 + l15;
                uint2 w0, w1;
                w0.x = (uint32_t)pb[0] | ((uint32_t)pb[1] << 16);
                w0.y = (uint32_t)pb[2] | ((uint32_t)pb[3] << 16);
                w1.x = (uint32_t)pb[4] | ((uint32_t)pb[5] << 16);
                w1.y = (uint32_t)pb[6] | ((uint32_t)pb[7] << 16);
                *(uint2*)&Ps[cur][row][quad * 4] = w0;
                *(uint2*)&Ps[cur][row][16 + quad * 4] = w1;
                if (lane < 16) Al[cur][w * 16 + lane] = alpha;
            } else {
                if (lane < 16) Lb[w * 16 + lane] = l_r;   // drain iter: publish l
            }
        } else {
            // ---- PV waves: issue all async staging FIRST (full-iteration latency cover)
            if (kt < 63) {                 // K tile kt+1 -> Ks[prv] (read next iter by QK)
                #pragma unroll
                for (int i = 0; i < 4; ++i) {
                    int row = pw * 4 + i;
                    gl_lds16(Kb + (size_t)((kt + 1) * 32 + row) * C_DIM + lane * 8, &Ks[prv][row][0]);
                }
            }
            if (kt < 64) {                 // V tile kt -> Vs[cur] (read next iter by PV)
                int k0 = kt * 32;
                #pragma unroll
                for (int i = 0; i < 4; ++i) {
                    int r0 = (pw * 4 + i) * 16;
                    gl_lds16(Vt + (size_t)(r0 + (lane >> 2)) * L_SEQ + k0 + (lane & 3) * 8,
                             &Vs[cur][r0][0]);
                }
            }
            if (kt > 0) {
                // ---- PV for tile kt-1 from Ps/Al/Vs[prv]
                bf16x8 pf[4];
                #pragma unroll
                for (int qi = 0; qi < 4; ++qi)
                    pf[qi] = *(const bf16x8*)&Ps[prv][qi * 16 + l15][quad * 8];
                #pragma unroll
                for (int qi = 0; qi < 4; ++qi) {
                    float4 av = *(const float4*)&Al[prv][qi * 16 + quad * 4];
                    #pragma unroll
                    for (int nt = 0; nt < 4; ++nt) {
                        acc[qi][nt][0] *= av.x; acc[qi][nt][1] *= av.y;
                        acc[qi][nt][2] *= av.z; acc[qi][nt][3] *= av.w;
                    }
                }
                bf16x8 vf[4];
                #pragma unroll
                for (int nt = 0; nt < 4; ++nt)
                    vf[nt] = *(const bf16x8*)&Vs[prv][d0 + nt * 16 + l15][quad * 8];
                __builtin_amdgcn_s_setprio(1);
                #pragma unroll
                for (int nt = 0; nt < 4; ++nt)
                    #pragma unroll
                    for (int qi = 0; qi < 4; ++qi)
                        acc[qi][nt] = __builtin_amdgcn_mfma_f32_16x16x32_bf16(pf[qi], vf[nt], acc[qi][nt], 0, 0, 0);
                __builtin_amdgcn_s_setprio(0);
            }
        }
        __syncthreads();   // P/alpha handoff + drains K & V DMA vmcnt
    }
    // epilogue: PV waves normalize and write their d-slice
    if (!isQK) {
        #pragma unroll
        for (int qi = 0; qi < 4; ++qi) {
            float4 lv = *(const float4*)&Lb[qi * 16 + quad * 4];
            float inv[4] = {1.f / lv.x, 1.f / lv.y, 1.f / lv.z, 1.f / lv.w};
            #pragma unroll
            for (int r = 0; r < 4; ++r) {
                int m = qt * 64 + qi * 16 + quad * 4 + r;
                #pragma unroll
                for (int nt = 0; nt < 4; ++nt)
                    Ob[(size_t)m * 512 + d0 + nt * 16 + l15] = f2bf(acc[qi][nt][r] * inv[r]);
            }
        }
    }
}

extern "C" void kernel_launch(void* const* d_in, const int* in_sizes, int n_in,
                              void* d_out, int out_size, void* d_ws, size_t ws_size,
                              hipStream_t stream) {
    const float* x     = (const float*)d_in[0];
    const float* gamma = (const float*)d_in[1];
    const float* beta  = (const float*)d_in[2];
    const float* wq    = (const float*)d_in[3];
    const float* bq    = (const float*)d_in[4];
    const float* wk    = (const float*)d_in[5];
    const float* bk    = (const float*)d_in[6];
    const float* wv    = (const float*)d_in[7];
    const float* bv    = (const float*)d_in[8];
    const float* wp    = (const float*)d_in[9];
    const float* bp    = (const float*)d_in[10];
    float* out = (float*)d_out;

    const size_t MC = (size_t)B_SZ * L_SEQ * C_DIM;   // 8,388,608 elems
    const size_t WC = (size_t)C_DIM * C_DIM;
    ushort_t* h     = (ushort_t*)d_ws;
    ushort_t* qb    = h     + MC;
    ushort_t* kb    = qb    + MC;
    ushort_t* vbuf  = kb    + MC;   // attention output O
    ushort_t* vtb   = vbuf  + MC;   // V^T [b][d][l] (written directly by gemm_qkv V-blocks)
    ushort_t* wqkvT = vtb   + MC;   // [1536][512] bf16 (wq^T | wk^T | wv^T)
    ushort_t* wpT   = wqkvT + 3 * WC;
    float* sums     = (float*)(wpT + WC);

    conv_stats<<<dim3(768), dim3(256), 0, stream>>>(wq, wk, wv, wp, wqkvT, wpT, x, sums);
    gn_apply<<<dim3(4096), dim3(256), 0, stream>>>(x, gamma, beta, sums, h);

    // fused QKV GEMM (QK blocks 0-1023, V^T blocks 1024-1535), XCD-swizzled
    gemm_qkv<<<dim3(1536), dim3(256), 0, stream>>>(h, wqkvT, bq, bk, bv, qb, kb, vtb);

    attn11<<<dim3(256), dim3(768), 0, stream>>>(qb, kb, vtb, vbuf);

    // PROJ GEMM: f32 out + residual h, XCD-swizzled
    gemm_proj<<<dim3(512), dim3(256), 0, stream>>>(vbuf, wpT, bp, h, out);
}